// Round 4
// baseline (204.582 us; speedup 1.0000x reference)
//
#include <hip/hip_runtime.h>
#include <cstdint>

// Poincare-ball MLR:  out[row][n] = S_n * asinh( lam_row * inner[row][n] * A_n - (lam_row-1) * B_n )
//   inner = X @ Z  (bf16 MFMA),  lam_row = 2/(1 - ||x_row||^2)
//   A_n = cosh(2 r_n)/znorm_n,  B_n = sinh(2 r_n),  S_n = 2 znorm_n   (c = 1)
//
// R8 (resubmit; round-3 bench was an infra failure, no kernel verdict):
// exact revert to the measured-good R5b (120.8us) + ONE change:
//     2 row-tiles per block (1024 blocks), Zt staged once per block.
// R6/R7 post-mortem: swapped epilogue + nt stores + sched_barrier all regressed
// (R7 counters: main 41.5us, WRITE 87MB vs 67 ideal = 1.33x write amplification
// from nt partial-line streams; VGPR_Count 44 = degenerate allocation).
// This round: single variable, mechanism = amortize per-block startup serial
// phase {stage -> vmcnt-drain barrier -> X latency} from 8/CU to 4/CU (all
// resident, zero churn). Inner tile code is byte-identical R5b; #pragma
// unroll 1 pins per-iteration register pressure to the R5b profile.

typedef __attribute__((ext_vector_type(8))) short short8;   // 8 bf16 = 4 VGPRs (MFMA A/B frag)
typedef __attribute__((ext_vector_type(4))) float floatx4;  // MFMA C/D frag

#define D 128

__device__ inline unsigned bf16_rhu(float f) {   // round-half-up to bf16, bit trick (2 VALU)
    return (__float_as_uint(f) + 0x8000u) >> 16;
}
__device__ inline unsigned pack2(float lo, float hi) {
    return bf16_rhu(lo) | (bf16_rhu(hi) << 16);
}

// ---------------- prep: PRE-SWIZZLED bf16 Zt + packed per-col constants ----------------
// zt_sw chunk layout: 16B chunk (row, c) stored at chunk index row*16 + (c ^ (row&7)),
// so a linear global_load_lds stage reproduces the swizzled LDS layout.
// abs4[n] = { cosh(2r)/zn, sinh(2r), 2*zn*ln2, 0 }   (ln2 folded: asinh via log2)
__global__ void hmlr_prep(const float* __restrict__ z, const float* __restrict__ r,
                          unsigned short* __restrict__ zt_sw, float4* __restrict__ abs4) {
    int n = blockIdx.x;
    int k = threadIdx.x;
    float v = z[k * D + n];                          // column n of Z
    int c = k >> 3, p = k & 7;
    zt_sw[n * D + ((c ^ (n & 7)) << 3) + p] = (unsigned short)bf16_rhu(v);
    float pw = v * v;
    #pragma unroll
    for (int off = 32; off >= 1; off >>= 1) pw += __shfl_down(pw, off, 64);
    __shared__ float tmp[2];
    if ((k & 63) == 0) tmp[k >> 6] = pw;
    __syncthreads();
    if (k == 0) {
        float ss = tmp[0] + tmp[1];
        float zn = fmaxf(sqrtf(ss), 1e-15f);
        float tc = 2.0f * r[n];                      // 2*sqrt(c)*r, c=1
        abs4[n] = make_float4(coshf(tc) / zn, sinhf(tc),
                              2.0f * zn * 0.69314718055994531f, 0.0f);
    }
}

// ---------------- main: 1024 blocks x 256 threads, 2 tiles x (4 waves x 16 rows) ------
__global__ __launch_bounds__(256, 5) void hmlr_main(const float* __restrict__ x,
                                                    const unsigned short* __restrict__ zt_sw,
                                                    const float4* __restrict__ abs4,
                                                    float* __restrict__ out) {
    __shared__ __align__(16) unsigned char lds[32768];   // Zt bf16, swizzled 16B chunks

    const int t    = threadIdx.x;
    const int w    = t >> 6;         // wave 0..3
    const int l    = t & 63;
    const int quad = l >> 4;         // 0..3
    const int l15  = l & 15;
    const int l7   = l & 7;

    // ---- Zt -> LDS: async direct-to-LDS, 1KB per wave-instruction, 8 per wave ----
    // Staged ONCE per block, reused by both row-tiles.
#if __has_builtin(__builtin_amdgcn_global_load_lds)
    #pragma unroll
    for (int i = 0; i < 8; ++i) {
        int ci = w * 512 + i * 64 + l;               // 16B chunk index 0..2047
        __builtin_amdgcn_global_load_lds(
            (const __attribute__((address_space(1))) unsigned int*)(zt_sw + (ci << 3)),
            (__attribute__((address_space(3))) unsigned int*)(lds + ((w * 512 + i * 64) << 4)),
            16, 0, 0);
    }
#else
    #pragma unroll
    for (int i = 0; i < 8; ++i) {
        int ci = w * 512 + i * 64 + l;
        *reinterpret_cast<uint4*>(&lds[ci << 4]) = reinterpret_cast<const uint4*>(zt_sw)[ci];
    }
#endif
    __syncthreads();

    #pragma unroll 1                                 // keep per-tile pressure == R5b profile
    for (int tile = 0; tile < 2; ++tile) {
        // ---- X direct from global in MFMA A-layout: lane(m=l15) reads row's k-octets ----
        const int rowbase = blockIdx.x * 128 + tile * 64 + w * 16;   // this wave's 16 rows
        const float* xrow = x + (size_t)(rowbase + l15) * D + (quad << 3);
        float4 xv[8];
        #pragma unroll
        for (int kc = 0; kc < 4; ++kc) {
            xv[2 * kc]     = *reinterpret_cast<const float4*>(xrow + (kc << 5));
            xv[2 * kc + 1] = *reinterpret_cast<const float4*>(xrow + (kc << 5) + 4);
        }

        // ---- ||x_row||^2 fp32 (pre-cast): lane partial + combine quads sharing l15 ----
        float ssq = 0.f;
        #pragma unroll
        for (int i = 0; i < 8; ++i)
            ssq += xv[i].x * xv[i].x + xv[i].y * xv[i].y + xv[i].z * xv[i].z + xv[i].w * xv[i].w;
        ssq += __shfl_xor(ssq, 16);
        ssq += __shfl_xor(ssq, 32);  // every lane: ssq of row (rowbase + l15)

        // ---- bf16 A-frags, 2.5 VALU/value bit-trick pack ----
        short8 afrag[4];
        #pragma unroll
        for (int kc = 0; kc < 4; ++kc) {
            union { short8 s8; unsigned u[4]; } af;
            af.u[0] = pack2(xv[2 * kc].x,     xv[2 * kc].y);
            af.u[1] = pack2(xv[2 * kc].z,     xv[2 * kc].w);
            af.u[2] = pack2(xv[2 * kc + 1].x, xv[2 * kc + 1].y);
            af.u[3] = pack2(xv[2 * kc + 1].z, xv[2 * kc + 1].w);
            afrag[kc] = af.s8;
        }

        // ---- MFMA 16x16x32 bf16, per-kc B preload (8 frags in regs -> ILP) ----
        floatx4 acc[8];
        #pragma unroll
        for (int nt = 0; nt < 8; ++nt) acc[nt] = (floatx4){0.f, 0.f, 0.f, 0.f};

        #pragma unroll
        for (int kc = 0; kc < 4; ++kc) {
            short8 b[8];
            #pragma unroll
            for (int nt = 0; nt < 8; ++nt)
                b[nt] = *reinterpret_cast<const short8*>(
                    &lds[((nt * 16 + l15) << 8) + (((quad + (kc << 2)) ^ l7) << 4)]);
            #pragma unroll
            for (int nt = 0; nt < 8; ++nt)
                acc[nt] = __builtin_amdgcn_mfma_f32_16x16x32_bf16(afrag[kc], b[nt], acc[nt], 0, 0, 0);
        }

        // ---- epilogue: C/D layout col = lane&15, row = quad*4 + reg; direct scatter stores ----
        float4 cst[8];
        #pragma unroll
        for (int nt = 0; nt < 8; ++nt) cst[nt] = abs4[nt * 16 + l15];

        #pragma unroll
        for (int reg = 0; reg < 4; ++reg) {
            float rss = __shfl(ssq, (quad << 2) | reg);  // ssq of row quad*4+reg
            float lam = 2.0f / (1.0f - rss);
            float lm1 = lam - 1.0f;
            float* orow = out + (size_t)(rowbase + (quad << 2) + reg) * D + l15;
            #pragma unroll
            for (int nt = 0; nt < 8; ++nt) {
                float arg = __fmaf_rn(lam * acc[nt][reg], cst[nt].x, -lm1 * cst[nt].y);
                float a   = fabsf(arg);
                float as  = __log2f(a + __fsqrt_rn(__fmaf_rn(a, a, 1.0f)));  // asinh/ln2
                orow[nt * 16] = copysignf(as, arg) * cst[nt].z;              // cst.z = 2 zn ln2
            }
        }
    }
}

extern "C" void kernel_launch(void* const* d_in, const int* in_sizes, int n_in,
                              void* d_out, int out_size, void* d_ws, size_t ws_size,
                              hipStream_t stream) {
    const float* x = (const float*)d_in[0];   // [16*8192, 128] fp32
    const float* z = (const float*)d_in[1];   // [128, 128] fp32
    const float* r = (const float*)d_in[2];   // [128] fp32
    float* out = (float*)d_out;

    // ws layout: zt_sw bf16 swizzled [128][128] (32768 B) | abs4 float4[128] (2048 B)
    char* wsb = (char*)d_ws;
    unsigned short* zt_sw = (unsigned short*)wsb;
    float4* abs4 = (float4*)(wsb + 128 * D * sizeof(unsigned short));

    hmlr_prep<<<128, 128, 0, stream>>>(z, r, zt_sw, abs4);

    const int n_rows = in_sizes[0] / D;       // 131072
    hmlr_main<<<n_rows / 128, 256, 0, stream>>>(x, zt_sw, abs4, out);
}

// Round 5
// 120.294 us; speedup vs baseline: 1.7007x; 1.7007x over previous
//
#include <hip/hip_runtime.h>
#include <cstdint>

// Poincare-ball MLR:  out[row][n] = S_n * asinh( lam_row * inner[row][n] * A_n - (lam_row-1) * B_n )
//   inner = X @ Z  (bf16 MFMA),  lam_row = 2/(1 - ||x_row||^2)
//   A_n = cosh(2 r_n)/znorm_n,  B_n = sinh(2 r_n),  S_n = 2 znorm_n   (c = 1)
//
// R9: byte-for-byte restore of the measured-best R5b (120.8 us).
// Post-mortems R6/R7/R8: every perturbation of this source form (swapped
// epilogue, nt stores, sched_barrier, 2-tile outer loop) tipped the register
// allocator off a cliff -> scratch spill (R8 counters: VGPR_Count 48,
// FETCH 162MB = 2.4x ideal, WRITE 194MB = 2.9x ideal, occupancy 39% from
// private-segment cap). This source form is a compiler-local optimum.
// Floor arithmetic: fills 86.5us (harness, at HW write ceiling) + prep ~2us
// + main ~30us (vs 21.3us BW roofline) + gaps ~2us = ~121us.
//
// (1) epilogue = R2/R3-proven direct scatter stores;
// (2) X never touches LDS: A-frags gathered from global in MFMA A-layout,
//     ssq in fp32 via 2 shfl_xor, cheap bit-trick bf16 pack;
// (3) LDS = Zt only (32KB) staged by async global_load_lds width=16 from a
//     PRE-SWIZZLED ws copy -> 5 blocks/CU (20 waves/CU), barrier waits on
//     L2-hot Zt only; per-kc B-frag preload for ILP. launch_bounds(256,5).

typedef __attribute__((ext_vector_type(8))) short short8;   // 8 bf16 = 4 VGPRs (MFMA A/B frag)
typedef __attribute__((ext_vector_type(4))) float floatx4;  // MFMA C/D frag

#define D 128

__device__ inline unsigned bf16_rhu(float f) {   // round-half-up to bf16, bit trick (2 VALU)
    return (__float_as_uint(f) + 0x8000u) >> 16;
}
__device__ inline unsigned pack2(float lo, float hi) {
    return bf16_rhu(lo) | (bf16_rhu(hi) << 16);
}

// ---------------- prep: PRE-SWIZZLED bf16 Zt + packed per-col constants ----------------
// zt_sw chunk layout: 16B chunk (row, c) stored at chunk index row*16 + (c ^ (row&7)),
// so a linear global_load_lds stage reproduces the swizzled LDS layout.
// abs4[n] = { cosh(2r)/zn, sinh(2r), 2*zn*ln2, 0 }   (ln2 folded: asinh via log2)
__global__ void hmlr_prep(const float* __restrict__ z, const float* __restrict__ r,
                          unsigned short* __restrict__ zt_sw, float4* __restrict__ abs4) {
    int n = blockIdx.x;
    int k = threadIdx.x;
    float v = z[k * D + n];                          // column n of Z
    int c = k >> 3, p = k & 7;
    zt_sw[n * D + ((c ^ (n & 7)) << 3) + p] = (unsigned short)bf16_rhu(v);
    float pw = v * v;
    #pragma unroll
    for (int off = 32; off >= 1; off >>= 1) pw += __shfl_down(pw, off, 64);
    __shared__ float tmp[2];
    if ((k & 63) == 0) tmp[k >> 6] = pw;
    __syncthreads();
    if (k == 0) {
        float ss = tmp[0] + tmp[1];
        float zn = fmaxf(sqrtf(ss), 1e-15f);
        float tc = 2.0f * r[n];                      // 2*sqrt(c)*r, c=1
        abs4[n] = make_float4(coshf(tc) / zn, sinhf(tc),
                              2.0f * zn * 0.69314718055994531f, 0.0f);
    }
}

// ---------------- main: 2048 blocks x 256 threads, 4 waves x 16 rows = 64 rows/block ------
__global__ __launch_bounds__(256, 5) void hmlr_main(const float* __restrict__ x,
                                                    const unsigned short* __restrict__ zt_sw,
                                                    const float4* __restrict__ abs4,
                                                    float* __restrict__ out) {
    __shared__ __align__(16) unsigned char lds[32768];   // Zt bf16, swizzled 16B chunks

    const int t    = threadIdx.x;
    const int w    = t >> 6;         // wave 0..3
    const int l    = t & 63;
    const int quad = l >> 4;         // 0..3
    const int l15  = l & 15;
    const int l7   = l & 7;

    // ---- Zt -> LDS: async direct-to-LDS, 1KB per wave-instruction, 8 per wave ----
#if __has_builtin(__builtin_amdgcn_global_load_lds)
    #pragma unroll
    for (int i = 0; i < 8; ++i) {
        int ci = w * 512 + i * 64 + l;               // 16B chunk index 0..2047
        __builtin_amdgcn_global_load_lds(
            (const __attribute__((address_space(1))) unsigned int*)(zt_sw + (ci << 3)),
            (__attribute__((address_space(3))) unsigned int*)(lds + ((w * 512 + i * 64) << 4)),
            16, 0, 0);
    }
#else
    #pragma unroll
    for (int i = 0; i < 8; ++i) {
        int ci = w * 512 + i * 64 + l;
        *reinterpret_cast<uint4*>(&lds[ci << 4]) = reinterpret_cast<const uint4*>(zt_sw)[ci];
    }
#endif
    __syncthreads();

    // ---- X direct from global in MFMA A-layout: lane(m=l15) reads row's k-octets ----
    const int rowbase = blockIdx.x * 64 + w * 16;    // this wave's 16 rows
    const float* xrow = x + (size_t)(rowbase + l15) * D + (quad << 3);
    float4 xv[8];
    #pragma unroll
    for (int kc = 0; kc < 4; ++kc) {
        xv[2 * kc]     = *reinterpret_cast<const float4*>(xrow + (kc << 5));
        xv[2 * kc + 1] = *reinterpret_cast<const float4*>(xrow + (kc << 5) + 4);
    }

    // ---- ||x_row||^2 fp32 (pre-cast): lane partial + combine quads sharing l15 ----
    float ssq = 0.f;
    #pragma unroll
    for (int i = 0; i < 8; ++i)
        ssq += xv[i].x * xv[i].x + xv[i].y * xv[i].y + xv[i].z * xv[i].z + xv[i].w * xv[i].w;
    ssq += __shfl_xor(ssq, 16);
    ssq += __shfl_xor(ssq, 32);      // every lane: ssq of row (rowbase + l15)

    // ---- bf16 A-frags, 2.5 VALU/value bit-trick pack ----
    short8 afrag[4];
    #pragma unroll
    for (int kc = 0; kc < 4; ++kc) {
        union { short8 s8; unsigned u[4]; } af;
        af.u[0] = pack2(xv[2 * kc].x,     xv[2 * kc].y);
        af.u[1] = pack2(xv[2 * kc].z,     xv[2 * kc].w);
        af.u[2] = pack2(xv[2 * kc + 1].x, xv[2 * kc + 1].y);
        af.u[3] = pack2(xv[2 * kc + 1].z, xv[2 * kc + 1].w);
        afrag[kc] = af.s8;
    }

    // ---- MFMA 16x16x32 bf16, per-kc B preload (8 frags in regs -> ILP) ----
    floatx4 acc[8];
    #pragma unroll
    for (int nt = 0; nt < 8; ++nt) acc[nt] = (floatx4){0.f, 0.f, 0.f, 0.f};

    #pragma unroll
    for (int kc = 0; kc < 4; ++kc) {
        short8 b[8];
        #pragma unroll
        for (int nt = 0; nt < 8; ++nt)
            b[nt] = *reinterpret_cast<const short8*>(
                &lds[((nt * 16 + l15) << 8) + (((quad + (kc << 2)) ^ l7) << 4)]);
        #pragma unroll
        for (int nt = 0; nt < 8; ++nt)
            acc[nt] = __builtin_amdgcn_mfma_f32_16x16x32_bf16(afrag[kc], b[nt], acc[nt], 0, 0, 0);
    }

    // ---- epilogue: C/D layout col = lane&15, row = quad*4 + reg; direct scatter stores ----
    float4 cst[8];
    #pragma unroll
    for (int nt = 0; nt < 8; ++nt) cst[nt] = abs4[nt * 16 + l15];

    #pragma unroll
    for (int reg = 0; reg < 4; ++reg) {
        float rss = __shfl(ssq, (quad << 2) | reg);  // ssq of row quad*4+reg
        float lam = 2.0f / (1.0f - rss);
        float lm1 = lam - 1.0f;
        float* orow = out + (size_t)(rowbase + (quad << 2) + reg) * D + l15;
        #pragma unroll
        for (int nt = 0; nt < 8; ++nt) {
            float arg = __fmaf_rn(lam * acc[nt][reg], cst[nt].x, -lm1 * cst[nt].y);
            float a   = fabsf(arg);
            float as  = __log2f(a + __fsqrt_rn(__fmaf_rn(a, a, 1.0f)));  // asinh/ln2
            orow[nt * 16] = copysignf(as, arg) * cst[nt].z;              // cst.z = 2 zn ln2
        }
    }
}

extern "C" void kernel_launch(void* const* d_in, const int* in_sizes, int n_in,
                              void* d_out, int out_size, void* d_ws, size_t ws_size,
                              hipStream_t stream) {
    const float* x = (const float*)d_in[0];   // [16*8192, 128] fp32
    const float* z = (const float*)d_in[1];   // [128, 128] fp32
    const float* r = (const float*)d_in[2];   // [128] fp32
    float* out = (float*)d_out;

    // ws layout: zt_sw bf16 swizzled [128][128] (32768 B) | abs4 float4[128] (2048 B)
    char* wsb = (char*)d_ws;
    unsigned short* zt_sw = (unsigned short*)wsb;
    float4* abs4 = (float4*)(wsb + 128 * D * sizeof(unsigned short));

    hmlr_prep<<<128, 128, 0, stream>>>(z, r, zt_sw, abs4);

    const int n_rows = in_sizes[0] / D;       // 131072
    hmlr_main<<<n_rows / 64, 256, 0, stream>>>(x, zt_sw, abs4, out);
}